// Round 14
// baseline (5337.172 us; speedup 1.0000x reference)
//
#include <hip/hip_runtime.h>
#include <hip/hip_bf16.h>
#include <hip/hip_fp16.h>
#include <stdint.h>

namespace {

constexpr int Tn = 512, In = 256, Hn = 256, Kn = 512;
constexpr int ENTRY = 36864;   // px tile (cl,slot): 32KB data + 4KB tags

typedef __attribute__((ext_vector_type(8))) short bf16x8;
typedef __attribute__((ext_vector_type(4))) float f32x4;
typedef __attribute__((ext_vector_type(4))) unsigned int u32x4;

__device__ __forceinline__ float sigmoidf_(float x) { return 1.f / (1.f + __expf(-x)); }
__device__ __forceinline__ float tanhf_(float x)    { return 2.f / (1.f + __expf(-2.f * x)) - 1.f; }

__device__ __forceinline__ int swz(int c) { return c ^ ((c >> 4) & 15); }

// LDS-only barrier (R11-proven): no vmcnt drain on the critical path
__device__ __forceinline__ void bar_lds() {
    asm volatile("s_waitcnt lgkmcnt(0)\n\ts_barrier" ::: "memory");
}

__device__ __forceinline__ u32x4 ld16u_llc(const void* p) {
    u32x4 r;
    asm volatile("global_load_dwordx4 %0, %1, off sc1" : "=v"(r) : "v"(p) : "memory");
    return r;
}
__device__ __forceinline__ void stdw_llc(void* p, uint32_t v) {
    asm volatile("global_store_dword %0, %1, off sc1" :: "v"(p), "v"(v) : "memory");
}
__device__ __forceinline__ uint32_t lddw_llc(const void* p) {
    uint32_t r;
    asm volatile("global_load_dword %0, %1, off sc1\n\ts_waitcnt vmcnt(0)"
                 : "=v"(r) : "v"(p) : "memory");
    return r;
}
__device__ __forceinline__ bool tags8(u32x4 a, u32x4 b, uint32_t wt) {
    uint32_t d = (a.x ^ wt) | (a.y ^ wt) | (a.z ^ wt) | (a.w ^ wt)
               | (b.x ^ wt) | (b.y ^ wt) | (b.z ^ wt) | (b.w ^ wt);
    return (d & 0xFFFF0000u) == 0u;
}
__device__ __forceinline__ bf16x8 pack8(u32x4 a, u32x4 b) {
    union { uint32_t u[4]; bf16x8 v; } r;
    r.u[0] = (a.x & 0xFFFFu) | (a.y << 16);
    r.u[1] = (a.z & 0xFFFFu) | (a.w << 16);
    r.u[2] = (b.x & 0xFFFFu) | (b.y << 16);
    r.u[3] = (b.z & 0xFFFFu) | (b.w << 16);
    return r.v;
}

// ================= TIER 0: decoupled x-GEMM + single-CU recurrence ==========
// 256 WGs x 1024 thr. wg<16: CONSUMER cl=wg (16 batch rows, Wh in 128 VGPRs/thr,
// recurrence fully intra-CU). wg>=16: 240 PRODUCERS computing preactX(cl,t)
// tiles (f32 GEMM + bias -> f16) into a RING-deep ws buffer with per-thread
// tags; consumers prefetch ~always-hit. Pacing via prog[cl] (fire-forget sc1).

__global__ void pack_pipe(const float* __restrict__ W,
                          __hip_bfloat16* __restrict__ Wxf, __hip_bfloat16* __restrict__ Whf,
                          char* __restrict__ px, uint32_t* __restrict__ prog, int RING) {
    const int idx = blockIdx.x * 256 + threadIdx.x;    // 524288 threads
    if (idx < 262144) {
        const int e = idx & 7, fi = idx >> 3;
        const int lane = fi & 63, kb = (fi >> 6) & 7, wnt = fi >> 9;  // wnt=w*4+nt
        const int n = wnt * 16 + (lane & 15);
        const int k = kb * 32 + (lane >> 4) * 8 + e;
        Wxf[idx] = __float2bfloat16(W[(size_t)n * Kn + k]);
        Whf[idx] = __float2bfloat16(W[(size_t)n * Kn + 256 + k]);
    }
    if (idx < 16) prog[idx * 16] = 0u;
    // zero ALL px tags every launch (graph replays reuse ws; tag space repeats)
    const int NT = 16 * RING * 1024;
    for (int i = idx; i < NT; i += 524288)
        *(uint32_t*)(px + (size_t)(i >> 10) * ENTRY + 32768 + (size_t)(i & 1023) * 4) = 0u;
}

__global__ __launch_bounds__(1024, 1) void lstm_pipe(
    const float* __restrict__ X, const float* __restrict__ bias,
    const __hip_bfloat16* __restrict__ Wxf, const __hip_bfloat16* __restrict__ Whf,
    char* __restrict__ px, uint32_t* __restrict__ prog,
    float* __restrict__ out, int RING)
{
    __shared__ bf16x8 fragv[512];          // 8 KB A-frags (consumer: h; producer: x)
    __shared__ float preact[16][1154];     // 73856 B (P=1154: write-quad banks 0/8/16/24)
    // total 82 KB static LDS -> exactly 1 WG/CU (consumers never share a CU)

    const int tid = threadIdx.x, lane = tid & 63, w = tid >> 6;
    const int l15 = lane & 15;
    const int u = tid & 255, bq = tid >> 8;
    const int wg = blockIdx.x;

    if (wg < 16) {
        // ============================ CONSUMER ==============================
        const int cl = wg;
        bf16x8 wf[4][8];                               // Wh: 128 VGPRs
#pragma unroll
        for (int nt = 0; nt < 4; ++nt)
#pragma unroll
            for (int kb = 0; kb < 8; ++kb)
                wf[nt][kb] = *(const bf16x8*)(Whf + ((size_t)((w * 4 + nt) * 8 + kb) * 64 + lane) * 8);

        float c4[4] = {0.f, 0.f, 0.f, 0.f};
        if (tid < 512) { const bf16x8 z = {}; fragv[tid] = z; }   // h(-1)=0

        const char* pxbase = px + (size_t)cl * RING * ENTRY;
        // blocking fetch px(0)
        u32x4 c0, c1;
        {
            const char* pd = pxbase + (size_t)tid * 32;
            const char* pt = pxbase + 32768 + (size_t)tid * 4;
            uint32_t tg = 0; int gc = 0;
            do {
                asm volatile("global_load_dwordx4 %0, %3, off sc1\n\t"
                             "global_load_dwordx4 %1, %4, off sc1\n\t"
                             "global_load_dword %2, %5, off sc1\n\t"
                             "s_waitcnt vmcnt(0)"
                             : "=&v"(c0), "=&v"(c1), "=&v"(tg)
                             : "v"(pd), "v"(pd + 16), "v"(pt) : "memory");
                __builtin_amdgcn_sched_barrier(0);
            } while (tg != 1u && ++gc < (1 << 13));
        }
        // issue prefetch px(1)
        u32x4 n0, n1; uint32_t ntg;
        {
            const char* pd = pxbase + (size_t)(1 % RING) * ENTRY + (size_t)tid * 32;
            const char* pt = pxbase + (size_t)(1 % RING) * ENTRY + 32768 + (size_t)tid * 4;
            asm volatile("global_load_dwordx4 %0, %3, off sc1\n\t"
                         "global_load_dwordx4 %1, %4, off sc1\n\t"
                         "global_load_dword %2, %5, off sc1"
                         : "=&v"(n0), "=&v"(n1), "=&v"(ntg)
                         : "v"(pd), "v"(pd + 16), "v"(pt) : "memory");
        }
        uint32_t* myprog = prog + cl * 16;
        __syncthreads();

#pragma unroll 1
        for (int t = 0; t < Tn; ++t) {
            // ---- h-GEMM: preact_h = Wh @ h(t-1), all intra-CU ----
            f32x4 acc[4] = {};
            bf16x8 af[8];
#pragma unroll
            for (int i = 0; i < 8; ++i)
                af[i] = fragv[swz(i * 64 + lane)];
#pragma unroll
            for (int i = 0; i < 8; ++i)
#pragma unroll
                for (int nt = 0; nt < 4; ++nt)
                    acc[nt] = __builtin_amdgcn_mfma_f32_16x16x32_bf16(af[i], wf[nt][i], acc[nt], 0, 0, 0);
#pragma unroll
            for (int nt = 0; nt < 4; ++nt)
#pragma unroll
                for (int r = 0; r < 4; ++r)
                    preact[(lane >> 4) * 4 + r][w * 64 + nt * 16 + l15] = acc[nt][r];
            bar_lds();

            // ---- px(t+1) prefetch landed ~1 step ago; certify it ----
            asm volatile("s_waitcnt vmcnt(0)" ::: "memory");
            __builtin_amdgcn_sched_barrier(0);
            if (t < Tn - 1) {
                const uint32_t want = (uint32_t)(t + 2);   // tag of px(t+1)
                int gc = 0;
                while (ntg != want && gc++ < (1 << 13)) {  // rare slow path
                    const int s2 = (t + 1) % RING;
                    const char* pd = pxbase + (size_t)s2 * ENTRY + (size_t)tid * 32;
                    const char* pt = pxbase + (size_t)s2 * ENTRY + 32768 + (size_t)tid * 4;
                    asm volatile("global_load_dwordx4 %0, %3, off sc1\n\t"
                                 "global_load_dwordx4 %1, %4, off sc1\n\t"
                                 "global_load_dword %2, %5, off sc1\n\t"
                                 "s_waitcnt vmcnt(0)"
                                 : "=&v"(n0), "=&v"(n1), "=&v"(ntg)
                                 : "v"(pd), "v"(pd + 16), "v"(pt) : "memory");
                    __builtin_amdgcn_sched_barrier(0);
                }
            }

            // ---- gates: preact_h (LDS) + px(t) (regs, f16) ----
            union { u32x4 v; uint32_t a[4]; } U0, U1;
            U0.v = c0; U1.v = c1;
#pragma unroll
            for (int p = 0; p < 4; ++p) {
                const int b = bq * 4 + p;
                float pr[4];
#pragma unroll
                for (int k = 0; k < 4; ++k) {
                    const int d = p * 2 + (k >> 1);
                    const uint32_t wd = (d < 4) ? U0.a[d] : U1.a[d - 4];
                    union { uint16_t us; __half hh; } cvh;
                    cvh.us = (uint16_t)((k & 1) ? (wd >> 16) : (wd & 0xFFFFu));
                    pr[k] = __half2float(cvh.hh) + preact[b][u + 256 * k];
                }
                const float ai  = sigmoidf_(pr[0]);
                const float aj  = tanhf_(pr[1]);
                const float afv = sigmoidf_(pr[2]);
                const float ao  = sigmoidf_(pr[3]);
                const float cn  = ai * aj + c4[p] * afv;
                c4[p] = cn;
                const float hn  = ao * tanhf_(cn);
                if (t < Tn - 1) {
                    union { __hip_bfloat16 bh; uint16_t us; } cv;
                    cv.bh = __float2bfloat16(hn);
                    const int chunk = (u >> 5) * 64 + ((u >> 3) & 3) * 16 + b;
                    *(uint16_t*)((char*)fragv + swz(chunk) * 16 + (u & 7) * 2) = cv.us;
                } else {
                    out[(size_t)(cl * 16 + b) * Hn + u] = hn;
                }
            }
            // rotate prefetch buffers; issue px(t+2)
            c0 = n0; c1 = n1;
            if (t + 2 < Tn) {
                const int s2 = (t + 2) % RING;
                const char* pd = pxbase + (size_t)s2 * ENTRY + (size_t)tid * 32;
                const char* pt = pxbase + (size_t)s2 * ENTRY + 32768 + (size_t)tid * 4;
                asm volatile("global_load_dwordx4 %0, %3, off sc1\n\t"
                             "global_load_dwordx4 %1, %4, off sc1\n\t"
                             "global_load_dword %2, %5, off sc1"
                             : "=&v"(n0), "=&v"(n1), "=&v"(ntg)
                             : "v"(pd), "v"(pd + 16), "v"(pt) : "memory");
            }
            if (tid == 0)
                stdw_llc(myprog, (uint32_t)(t + 1));   // consumed px(t)
            bar_lds();
        }
    } else {
        // ============================ PRODUCER ==============================
        bf16x8 wf[4][8];                               // Wx: 128 VGPRs
#pragma unroll
        for (int nt = 0; nt < 4; ++nt)
#pragma unroll
            for (int kb = 0; kb < 8; ++kb)
                wf[nt][kb] = *(const bf16x8*)(Wxf + ((size_t)((w * 4 + nt) * 8 + kb) * 64 + lane) * 8);
        float bslot[4];
#pragma unroll
        for (int nt = 0; nt < 4; ++nt)
            bslot[nt] = bias[w * 64 + nt * 16 + l15];

        __syncthreads();

#pragma unroll 1
        for (int tk = wg - 16; tk < 16 * Tn; tk += 240) {
            const int cl = tk & 15, t = tk >> 4, slot = t % RING;
            // ring-slot reuse gate: previous occupant (t-RING) must be consumed
            if (t >= RING) {
                const uint32_t need = (uint32_t)(t - RING + 1);
                int gc = 0;
                for (;;) {
                    const uint32_t v = lddw_llc(prog + cl * 16);
                    if (v >= need || ++gc >= (1 << 13)) break;
                    __builtin_amdgcn_s_sleep(8);
                }
            }
            // stage x(cl, t): wave = batch row, lanes cover 256 cols
            {
                const int b = w;                        // tid>>6
                const int c0i = lane * 4;
                const float4 xv = *(const float4*)(X + ((size_t)(cl * 16 + b) * Tn + t) * In + c0i);
                __hip_bfloat16 tmp[4];
                tmp[0] = __float2bfloat16(xv.x); tmp[1] = __float2bfloat16(xv.y);
                tmp[2] = __float2bfloat16(xv.z); tmp[3] = __float2bfloat16(xv.w);
                const int chunk = (c0i >> 5) * 64 + ((c0i >> 3) & 3) * 16 + b;
                *(ushort4*)((char*)fragv + swz(chunk) * 16 + (c0i & 7) * 2) = *(const ushort4*)tmp;
            }
            bar_lds();
            // x-GEMM (+bias)
            f32x4 acc[4];
#pragma unroll
            for (int nt = 0; nt < 4; ++nt)
                acc[nt] = f32x4{bslot[nt], bslot[nt], bslot[nt], bslot[nt]};
            bf16x8 af[8];
#pragma unroll
            for (int i = 0; i < 8; ++i)
                af[i] = fragv[swz(i * 64 + lane)];
#pragma unroll
            for (int i = 0; i < 8; ++i)
#pragma unroll
                for (int nt = 0; nt < 4; ++nt)
                    acc[nt] = __builtin_amdgcn_mfma_f32_16x16x32_bf16(af[i], wf[nt][i], acc[nt], 0, 0, 0);
#pragma unroll
            for (int nt = 0; nt < 4; ++nt)
#pragma unroll
                for (int r = 0; r < 4; ++r)
                    preact[(lane >> 4) * 4 + r][w * 64 + nt * 16 + l15] = acc[nt][r];
            bar_lds();
            // shuffle -> f16 entry (same tid<->(u,bq) map as consumer), store + tag
            uint32_t dw[8];
#pragma unroll
            for (int p = 0; p < 4; ++p) {
                const int b = bq * 4 + p;
#pragma unroll
                for (int k2 = 0; k2 < 2; ++k2) {
                    union { __half h2[2]; uint32_t u32; } pk;
                    pk.h2[0] = __float2half(preact[b][u + 256 * (2 * k2)]);
                    pk.h2[1] = __float2half(preact[b][u + 256 * (2 * k2 + 1)]);
                    dw[p * 2 + k2] = pk.u32;
                }
            }
            char* pd = px + ((size_t)cl * RING + slot) * ENTRY + (size_t)tid * 32;
            char* pt = px + ((size_t)cl * RING + slot) * ENTRY + 32768 + (size_t)tid * 4;
            const u32x4 D0 = {dw[0], dw[1], dw[2], dw[3]};
            const u32x4 D1 = {dw[4], dw[5], dw[6], dw[7]};
            asm volatile("global_store_dwordx4 %0, %2, off sc1\n\t"
                         "global_store_dwordx4 %1, %3, off sc1"
                         :: "v"(pd), "v"(pd + 16), "v"(D0), "v"(D1) : "memory");
            asm volatile("s_waitcnt vmcnt(0)" ::: "memory");   // data visible before tag
            stdw_llc(pt, (uint32_t)(t + 1));
            bar_lds();   // preact/frag reads done before next tile overwrites
        }
    }
}

// ============= TIER 1: R13 (XCD clustering + sc1 tag protocol, 1118us) ======
__global__ void pack_w_tag(const float* __restrict__ W, __hip_bfloat16* __restrict__ Wpf,
                           unsigned long long* __restrict__ hz, uint32_t* __restrict__ tab) {
    int idx  = blockIdx.x * 256 + threadIdx.x;
    int lane = idx & 63;
    int kb   = (idx >> 6) & 15;
    int nt2  = idx >> 10;
    int g = nt2 & 3, wu = (nt2 >> 2) & 3, jj = nt2 >> 4;
    int row = g * 256 + jj * 64 + wu * 16 + (lane & 15);
    int k0  = kb * 32 + (lane >> 4) * 8;
    const float* src = W + (size_t)row * Kn + k0;
    union { __hip_bfloat16 h[8]; bf16x8 v; } u;
#pragma unroll
    for (int e = 0; e < 8; ++e) u.h[e] = __float2bfloat16(src[e]);
    *(bf16x8*)(Wpf + (size_t)idx * 8) = u.v;
    hz[idx] = 0ULL;
    if (blockIdx.x == 0 && threadIdx.x < 256) {
        tab[threadIdx.x] = 0u;
        tab[256 + threadIdx.x] = 0u;
    }
}

__global__ __launch_bounds__(512, 2) void lstm_xcd(
    const float* __restrict__ X, const float* __restrict__ bias,
    const __hip_bfloat16* __restrict__ Wpf, char* __restrict__ hbuf,
    uint32_t* __restrict__ tab, float* __restrict__ out)
{
    __shared__ bf16x8 AfrX[2][512];
    __shared__ bf16x8 AfrH[512];
    __shared__ f32x4 Red[4][4][64];
    __shared__ uint32_t roleSh;

    const int tid = threadIdx.x, lane = tid & 63, w8 = tid >> 6;
    const int wu = w8 & 3, ks = w8 >> 2;
    const int l15 = lane & 15, lk = lane >> 4;
    const int wg = blockIdx.x;
    uint32_t* xcdtab = tab;
    uint32_t* asgn   = tab + 256;

    uint32_t xcc;
    asm volatile("s_getreg_b32 %0, hwreg(HW_REG_XCC_ID)" : "=s"(xcc));
    if (tid == 0) {
        uint32_t v = (xcc & 7) + 1;
        asm volatile("global_store_dword %0, %1, off sc1\n\ts_waitcnt vmcnt(0)"
                     :: "v"(xcdtab + wg), "v"(v) : "memory");
    }
    if (wg == 0) {
        uint32_t* xtabL = (uint32_t*)&AfrX[0][0];
        uint32_t* asgnL = xtabL + 256;
        if (tid < 256) {
            uint32_t v = 0;
            for (uint32_t g2 = 0; g2 < (1u << 16); ++g2) {
                v = lddw_llc(xcdtab + tid);
                if (v != 0) break;
            }
            xtabL[tid] = v;
            asgnL[tid] = 1u;
        }
        __syncthreads();
        if (tid == 0) {
            int cnt[8] = {0,0,0,0,0,0,0,0};
            int pend[8][4];
            int ncl = 0;
            for (int i = 0; i < 256 && ncl < 16; ++i) {
                const int x = (int)((xtabL[i] - 1u) & 7u);
                pend[x][cnt[x] & 3] = i;
                cnt[x]++;
                if ((cnt[x] & 3) == 0) {
                    for (int m = 0; m < 4; ++m)
                        asgnL[pend[x][m]] = 2u + (uint32_t)(ncl * 4 + m);
                    ncl++;
                }
            }
        }
        __syncthreads();
        if (tid < 256)
            asm volatile("global_store_dword %0, %1, off sc1"
                         :: "v"(asgn + tid), "v"(asgnL[tid]) : "memory");
        asm volatile("s_waitcnt vmcnt(0)" ::: "memory");
    }
    if (tid == 0) {
        uint32_t v = 0;
        for (uint32_t g2 = 0; g2 < (1u << 20); ++g2) {
            v = lddw_llc(asgn + wg);
            if (v != 0) break;
        }
        roleSh = v;
    }
    __syncthreads();
    const uint32_t role = roleSh;
    if (role < 2u) return;
    const int slot = (int)(role - 2u);
    const int cl = slot >> 2, j = slot & 3;
    __syncthreads();

    bf16x8 wf[4][8];
#pragma unroll
    for (int g = 0; g < 4; ++g)
#pragma unroll
        for (int i = 0; i < 8; ++i) {
            const int nt2 = (j * 4 + wu) * 4 + g, kb = ks * 8 + i;
            wf[g][i] = *(const bf16x8*)(Wpf + ((size_t)(nt2 * 16 + kb) * 64 + lane) * 8);
        }
    float bg[4];
#pragma unroll
    for (int g = 0; g < 4; ++g) bg[g] = bias[g * 256 + j * 64 + wu * 16 + l15];
    float c4[4] = {0.f, 0.f, 0.f, 0.f};
    {
        const bf16x8 z = {};
        AfrH[tid] = z;
    }
    const int b = wu * 4 + lk;
    const float* xbase = X + (size_t)(cl * 16 + b) * Tn * In;
    float4 xp[4];
    if (ks == 0) {
#pragma unroll
        for (int cc = 0; cc < 2; ++cc) {
            const int o8 = l15 + cc * 16;
            const float4 v0 = *(const float4*)(xbase + o8 * 8);
            const float4 v1 = *(const float4*)(xbase + o8 * 8 + 4);
            union { __hip_bfloat16 h[8]; bf16x8 v; } u;
            u.h[0] = __float2bfloat16(v0.x); u.h[1] = __float2bfloat16(v0.y);
            u.h[2] = __float2bfloat16(v0.z); u.h[3] = __float2bfloat16(v0.w);
            u.h[4] = __float2bfloat16(v1.x); u.h[5] = __float2bfloat16(v1.y);
            u.h[6] = __float2bfloat16(v1.z); u.h[7] = __float2bfloat16(v1.w);
            AfrX[0][swz(b + 16 * o8)] = u.v;
        }
#pragma unroll
        for (int cc = 0; cc < 2; ++cc) {
            const int o8 = l15 + cc * 16;
            xp[cc * 2]     = *(const float4*)(xbase + In + o8 * 8);
            xp[cc * 2 + 1] = *(const float4*)(xbase + In + o8 * 8 + 4);
        }
    }
    __syncthreads();

#pragma unroll 1
    for (int t = 0; t < Tn; ++t) {
        if (ks == 0) {
            f32x4 acc[4] = {};
            bf16x8 af[8];
#pragma unroll
            for (int i = 0; i < 8; ++i)
                af[i] = AfrX[t & 1][swz(i * 64 + lane)];
#pragma unroll
            for (int i = 0; i < 8; ++i)
#pragma unroll
                for (int g = 0; g < 4; ++g)
                    acc[g] = __builtin_amdgcn_mfma_f32_16x16x32_bf16(af[i], wf[g][i], acc[g], 0, 0, 0);
#pragma unroll
            for (int g = 0; g < 4; ++g) Red[wu][g][lane] = acc[g];
            if (t + 1 < Tn) {
#pragma unroll
                for (int cc = 0; cc < 2; ++cc) {
                    const int o8 = l15 + cc * 16;
                    union { __hip_bfloat16 h[8]; bf16x8 v; } u;
                    u.h[0] = __float2bfloat16(xp[cc * 2].x); u.h[1] = __float2bfloat16(xp[cc * 2].y);
                    u.h[2] = __float2bfloat16(xp[cc * 2].z); u.h[3] = __float2bfloat16(xp[cc * 2].w);
                    u.h[4] = __float2bfloat16(xp[cc * 2 + 1].x); u.h[5] = __float2bfloat16(xp[cc * 2 + 1].y);
                    u.h[6] = __float2bfloat16(xp[cc * 2 + 1].z); u.h[7] = __float2bfloat16(xp[cc * 2 + 1].w);
                    AfrX[(t + 1) & 1][swz(b + 16 * o8)] = u.v;
                }
            }
        } else if (t > 0 && wu != j) {
            const char* ib = hbuf + (size_t)(((cl * 4 + wu) * 2 + (t & 1)) * 4096)
                           + (lane & 15) * 256 + (lane >> 4) * 32;
            const uint32_t wt = ((uint32_t)t) << 16;
            u32x4 A0 = {}, A1 = {}, B0 = {}, B1 = {};
            bool f0 = false, f1 = false;
            int g2 = 0;
            for (;;) {
                if (!f0) { A0 = ld16u_llc(ib);       A1 = ld16u_llc(ib + 16); }
                if (!f1) { B0 = ld16u_llc(ib + 128); B1 = ld16u_llc(ib + 144); }
                asm volatile("s_waitcnt vmcnt(0)" ::: "memory");
                f0 = f0 || tags8(A0, A1, wt);
                f1 = f1 || tags8(B0, B1, wt);
                if (__all(f0 && f1) || ++g2 >= 4096) break;
            }
            __builtin_amdgcn_sched_barrier(0);
            AfrH[swz(wu * 128 + lane)]      = pack8(A0, A1);
            AfrH[swz(wu * 128 + 64 + lane)] = pack8(B0, B1);
        }
        bar_lds();

        uint16_t hb[4];
        if (ks == 0) {
            if (t + 2 < Tn) {
                const float* xs = xbase + (size_t)(t + 2) * In;
#pragma unroll
                for (int cc = 0; cc < 2; ++cc) {
                    const int o8 = l15 + cc * 16;
                    xp[cc * 2]     = *(const float4*)(xs + o8 * 8);
                    xp[cc * 2 + 1] = *(const float4*)(xs + o8 * 8 + 4);
                }
            }
        } else {
            f32x4 acc[4] = {};
            bf16x8 af[8];
#pragma unroll
            for (int i = 0; i < 8; ++i)
                af[i] = AfrH[swz(i * 64 + lane)];
#pragma unroll
            for (int i = 0; i < 8; ++i)
#pragma unroll
                for (int g = 0; g < 4; ++g)
                    acc[g] = __builtin_amdgcn_mfma_f32_16x16x32_bf16(af[i], wf[g][i], acc[g], 0, 0, 0);
#pragma unroll
            for (int g = 0; g < 4; ++g) acc[g] += Red[wu][g][lane];
#pragma unroll
            for (int r = 0; r < 4; ++r) {
                const float pi = acc[0][r] + bg[0];
                const float pj = acc[1][r] + bg[1];
                const float pf = acc[2][r] + bg[2];
                const float po = acc[3][r] + bg[3];
                const float ai = sigmoidf_(pi);
                const float aj = tanhf_(pj);
                const float afv = sigmoidf_(pf);
                const float ao = sigmoidf_(po);
                const float cn = ai * aj + c4[r] * afv;
                c4[r] = cn;
                const float hn = ao * tanhf_(cn);
                if (t < Tn - 1) {
                    union { __hip_bfloat16 bh; uint16_t u; } cv;
                    cv.bh = __float2bfloat16(hn);
                    hb[r] = cv.u;
                } else {
                    out[(size_t)(cl * 16 + lk * 4 + r) * Hn + j * 64 + wu * 16 + l15] = hn;
                }
            }
            if (t < Tn - 1) {
                asm volatile("s_waitcnt vmcnt(0)" ::: "memory");
                char* eb = hbuf + (size_t)(((cl * 4 + j) * 2 + ((t + 1) & 1)) * 4096);
                const uint32_t tagw = ((uint32_t)(t + 1)) << 16;
#pragma unroll
                for (int r = 0; r < 4; ++r)
                    stdw_llc(eb + (((lk * 4 + r) * 64 + wu * 16 + l15) << 2),
                             (uint32_t)hb[r] | tagw);
            }
        }
        bar_lds();

        if (ks == 1 && t < Tn - 1) {
#pragma unroll
            for (int r = 0; r < 4; ++r) {
                const int c = j * 128 + (wu >> 1) * 64
                            + ((wu & 1) * 2 + (l15 >> 3)) * 16 + lk * 4 + r;
                *(uint16_t*)((char*)AfrH + swz(c) * 16 + (l15 & 7) * 2) = hb[r];
            }
        }
    }
}

// ===================== TIER 3: R3 fallback ==================================
__global__ void pack_w(const float* __restrict__ W, __hip_bfloat16* __restrict__ Wp) {
    int idx = blockIdx.x * 256 + threadIdx.x;
    int e = idx & 7, l = (idx >> 3) & 63, kb = (idx >> 9) & 15, nt = idx >> 13;
    int n = nt * 16 + (l & 15);
    int k = kb * 32 + (l >> 4) * 8 + e;
    Wp[idx] = __float2bfloat16(W[n * Kn + k]);
}

__global__ __launch_bounds__(1024, 4) void lstm_fused(
    const float* __restrict__ X, const float* __restrict__ bias,
    const __hip_bfloat16* __restrict__ Wp, float* __restrict__ out)
{
    constexpr int LDA = Kn + 8;
    __shared__ __hip_bfloat16 A[16][LDA];
    const int tid = threadIdx.x, wv = tid >> 6, lane = tid & 63;
    const int l15 = lane & 15, lk = lane >> 4, b0 = blockIdx.x * 16;
    const __hip_bfloat16* wp[4];
#pragma unroll
    for (int g = 0; g < 4; ++g) wp[g] = Wp + (size_t)(g * 16 + wv) * (16 * 512) + lane * 8;
    float bslot[4];
#pragma unroll
    for (int g = 0; g < 4; ++g) bslot[g] = bias[g * 256 + wv * 16 + l15];
    float c[4], h[4];
#pragma unroll
    for (int r = 0; r < 4; ++r) { c[r] = 0.f; h[r] = 0.f; }
    const float* xptr = X + ((size_t)(b0 + wv) * Tn) * In + lane * 4;
#pragma unroll 1
    for (int t = 0; t < Tn; ++t) {
        __syncthreads();
        {
            const float4 v = *(const float4*)(xptr + (size_t)t * In);
            __hip_bfloat16 tmp[4];
            tmp[0] = __float2bfloat16(v.x); tmp[1] = __float2bfloat16(v.y);
            tmp[2] = __float2bfloat16(v.z); tmp[3] = __float2bfloat16(v.w);
            *(ushort4*)&A[wv][lane * 4] = *(const ushort4*)tmp;
        }
#pragma unroll
        for (int r = 0; r < 4; ++r)
            A[lk * 4 + r][In + wv * 16 + l15] = __float2bfloat16(h[r]);
        __syncthreads();
        f32x4 acc[4];
#pragma unroll
        for (int g = 0; g < 4; ++g) acc[g] = f32x4{bslot[g], bslot[g], bslot[g], bslot[g]};
        bf16x8 wbuf[2][4];
#pragma unroll
        for (int g = 0; g < 4; ++g) wbuf[0][g] = *(const bf16x8*)(wp[g]);
#pragma unroll
        for (int kb = 0; kb < 16; ++kb) {
            const int cur = kb & 1;
            if (kb < 15) {
#pragma unroll
                for (int g = 0; g < 4; ++g)
                    wbuf[cur ^ 1][g] = *(const bf16x8*)(wp[g] + (kb + 1) * 512);
            }
            const bf16x8 a = *(const bf16x8*)&A[l15][kb * 32 + lk * 8];
#pragma unroll
            for (int g = 0; g < 4; ++g)
                acc[g] = __builtin_amdgcn_mfma_f32_16x16x32_bf16(a, wbuf[cur][g], acc[g], 0, 0, 0);
        }
#pragma unroll
        for (int r = 0; r < 4; ++r) {
            const float ai = sigmoidf_(acc[0][r]);
            const float aj = tanhf_(acc[1][r]);
            const float af = sigmoidf_(acc[2][r]);
            const float ao = sigmoidf_(acc[3][r]);
            const float cn = ai * aj + c[r] * af;
            c[r] = cn;
            h[r] = ao * tanhf_(cn);
            if (t == Tn - 1)
                out[(size_t)(b0 + lk * 4 + r) * Hn + wv * 16 + l15] = h[r];
        }
    }
}

} // namespace

extern "C" void kernel_launch(void* const* d_in, const int* in_sizes, int n_in,
                              void* d_out, int out_size, void* d_ws, size_t ws_size,
                              hipStream_t stream) {
    const float* X    = (const float*)d_in[0];   // [256][512][256] f32
    const float* W    = (const float*)d_in[1];   // [1024][512] f32
    const float* bias = (const float*)d_in[2];   // [1024] f32

    // Tier 0 layout: Wxf @0 (512KB), Whf @0x80000 (512KB), prog @0x100000 (1KB pad 4KB),
    //                px ring @0x101000 (16 * RING * 36KB)
    const size_t PXOFF = 0x101000;
    if (ws_size >= PXOFF + (size_t)16 * 16 * ENTRY) {
        int RING = (int)((ws_size - PXOFF) / ((size_t)16 * ENTRY));
        if (RING > 64) RING = 64;
        __hip_bfloat16* Wxf  = (__hip_bfloat16*)d_ws;
        __hip_bfloat16* Whf  = (__hip_bfloat16*)((char*)d_ws + 0x80000);
        uint32_t*       prog = (uint32_t*)((char*)d_ws + 0x100000);
        char*           px   = (char*)d_ws + PXOFF;
        pack_pipe<<<dim3(2048), dim3(256), 0, stream>>>(W, Wxf, Whf, px, prog, RING);
        lstm_pipe<<<dim3(256), dim3(1024), 0, stream>>>(X, bias, Wxf, Whf, px, prog,
                                                        (float*)d_out, RING);
    } else if (ws_size >= (size_t)0x180000) {
        // Tier 1 (R13, 1118us): Wpf @0 (1MB), tagged hbuf @0x100000 (512KB)
        __hip_bfloat16* Wpf = (__hip_bfloat16*)d_ws;
        char*           hb  = (char*)d_ws + 0x100000;
        uint32_t*       tab = (uint32_t*)d_out;
        pack_w_tag<<<dim3(256), dim3(256), 0, stream>>>(W, Wpf, (unsigned long long*)hb, tab);
        lstm_xcd<<<dim3(256), dim3(512), 0, stream>>>(X, bias, Wpf, hb, tab, (float*)d_out);
    } else {
        __hip_bfloat16* Wp = (__hip_bfloat16*)d_ws;
        pack_w<<<dim3(2048), dim3(256), 0, stream>>>(W, Wp);
        lstm_fused<<<dim3(16), dim3(1024), 0, stream>>>(X, bias, Wp, (float*)d_out);
    }
}